// Round 3
// baseline (869.245 us; speedup 1.0000x reference)
//
#include <hip/hip_runtime.h>

#define BSHIFT 9
#define BW 512            // nodes per bucket
#define NBMAX 512         // max buckets (n <= 262144)
#define BLK 512
#define CHUNK 4096

// ---------------- pass B1: bucket histogram ----------------
__global__ __launch_bounds__(BLK) void k_bhist(const int* __restrict__ dst,
                                               int* __restrict__ bucketCount, int E) {
    __shared__ int h[NBMAX];
    int t = threadIdx.x;
    h[t] = 0;
    __syncthreads();
    int i = blockIdx.x * blockDim.x + t;
    int stride = gridDim.x * blockDim.x;
    for (int e = i; e < E; e += stride)
        atomicAdd(&h[dst[e] >> BSHIFT], 1);
    __syncthreads();
    if (h[t]) atomicAdd(&bucketCount[t], h[t]);
}

// ---------------- bucket scan (1 block) ----------------
__global__ __launch_bounds__(BLK) void k_bscan(const int* __restrict__ bucketCount,
                                               int* __restrict__ bucketBase,
                                               int* __restrict__ bucketCursor,
                                               int NB, int E) {
    __shared__ int lds[NBMAX];
    int t = threadIdx.x;
    lds[t] = (t < NB) ? bucketCount[t] : 0;
    __syncthreads();
    for (int d = 1; d < NBMAX; d <<= 1) {
        int v = (t >= d) ? lds[t - d] : 0;
        __syncthreads();
        lds[t] += v;
        __syncthreads();
    }
    int excl = (t == 0) ? 0 : lds[t - 1];
    if (t < NB) { bucketBase[t] = excl; bucketCursor[t] = excl; }
    if (t == NB) bucketBase[t] = E;
    if (t == 0 && NB == NBMAX) { /* never for n=200k */ }
}

// ---------------- pass B2: chunk counting-sort by dst-bucket, coalesced flush ----------------
__global__ __launch_bounds__(BLK) void k_bin(const int* __restrict__ src,
                                             const int* __restrict__ dst,
                                             int* __restrict__ bucketCursor,
                                             unsigned int* __restrict__ binned, int E) {
    __shared__ int hist[NBMAX];
    __shared__ int excl[NBMAX];
    __shared__ int cur[NBMAX];
    __shared__ int gbase[NBMAX];
    __shared__ unsigned int vals[CHUNK];
    __shared__ unsigned short bkt[CHUNK];
    int t = threadIdx.x;
    int base = blockIdx.x * CHUNK;
    int cnt = min(CHUNK, E - base);
    hist[t] = 0;
    __syncthreads();
    for (int k = t; k < cnt; k += BLK)
        atomicAdd(&hist[dst[base + k] >> BSHIFT], 1);
    __syncthreads();
    int hv = hist[t];
    excl[t] = hv;
    __syncthreads();
    for (int d = 1; d < NBMAX; d <<= 1) {
        int v = (t >= d) ? excl[t - d] : 0;
        __syncthreads();
        excl[t] += v;
        __syncthreads();
    }
    int ex = excl[t] - hv;
    __syncthreads();
    excl[t] = ex;
    cur[t] = ex;
    if (hv) gbase[t] = atomicAdd(&bucketCursor[t], hv);
    __syncthreads();
    for (int k = t; k < cnt; k += BLK) {
        int d = dst[base + k];
        int b = d >> BSHIFT;
        int r = atomicAdd(&cur[b], 1);
        vals[r] = ((unsigned int)src[base + k] << BSHIFT) | (unsigned int)(d & (BW - 1));
        bkt[r] = (unsigned short)b;
    }
    __syncthreads();
    for (int s = t; s < cnt; s += BLK) {
        int b = bkt[s];
        binned[gbase[b] + (s - excl[b])] = vals[s];
    }
}

// ---------------- pass C: per-bucket sort by src-bucket + deg/dinv/xd ----------------
__global__ __launch_bounds__(BLK) void k_sort(const unsigned int* __restrict__ binned,
                                              const int* __restrict__ bucketBase,
                                              const float* __restrict__ x,
                                              unsigned int* __restrict__ binned2,
                                              float* __restrict__ dinv,
                                              float* __restrict__ xd, int n) {
    __shared__ int hist[NBMAX];
    __shared__ int cursor[NBMAX];
    __shared__ int dhist[BW];
    int t = threadIdx.x;
    int b = blockIdx.x;
    int ebase = bucketBase[b];
    int ecnt = bucketBase[b + 1] - ebase;
    hist[t] = 0;
    if (t < BW) dhist[t] = 0;
    __syncthreads();
    for (int i = t; i < ecnt; i += BLK) {
        unsigned int v = binned[ebase + i];
        atomicAdd(&hist[v >> (2 * BSHIFT)], 1);
        atomicAdd(&dhist[v & (BW - 1)], 1);
    }
    __syncthreads();
    int hv = hist[t];
    cursor[t] = hv;
    __syncthreads();
    for (int d = 1; d < NBMAX; d <<= 1) {
        int v = (t >= d) ? cursor[t - d] : 0;
        __syncthreads();
        cursor[t] += v;
        __syncthreads();
    }
    int ex = cursor[t] - hv;
    __syncthreads();
    cursor[t] = ex;
    __syncthreads();
    for (int i = t; i < ecnt; i += BLK) {
        unsigned int v = binned[ebase + i];
        int r = atomicAdd(&cursor[v >> (2 * BSHIFT)], 1);
        binned2[ebase + r] = v;
    }
    int nodeBase = b << BSHIFT;
    if (t < BW && nodeBase + t < n) {
        int node = nodeBase + t;
        float r = rsqrtf((float)(dhist[t] + 1));
        dinv[node] = r;
        xd[node] = x[node] * r;
    }
}

// ---------------- layer 1: LDS scalar aggregate + transform -> t[N][16] ----------------
__global__ __launch_bounds__(BLK) void k_agg1(const unsigned int* __restrict__ binned2,
                                              const int* __restrict__ bucketBase,
                                              const float* __restrict__ xd,
                                              const float* __restrict__ dinv,
                                              const float* __restrict__ W1,
                                              const float* __restrict__ b1,
                                              const float* __restrict__ W2,
                                              float* __restrict__ t, int n) {
    __shared__ float sAcc[BW];
    __shared__ float sW1[16], sb1[16], sW2[256];
    int t0 = threadIdx.x;
    if (t0 < 16) { sW1[t0] = W1[t0]; sb1[t0] = b1[t0]; }
    if (t0 < 256) sW2[t0] = W2[t0];
    if (t0 < BW) sAcc[t0] = 0.f;
    __syncthreads();
    int b = blockIdx.x;
    int ebase = bucketBase[b];
    int ecnt = bucketBase[b + 1] - ebase;
    for (int i = t0; i < ecnt; i += BLK) {
        unsigned int v = binned2[ebase + i];
        atomicAdd(&sAcc[v & (BW - 1)], xd[v >> BSHIFT]);
    }
    __syncthreads();
    int nodeBase = b << BSHIFT;
    int nNodes = min(BW, n - nodeBase);
    int lane16 = t0 & 15;
    int grp = t0 >> 4;                    // 32 groups
    for (int it = 0; it < BW / 32; ++it) {
        int ln = it * 32 + grp;
        if (ln < nNodes) {
            int node = nodeBase + ln;
            float di = dinv[node];
            float s = di * (sAcc[ln] + xd[node]);
            float acc = 0.f;
#pragma unroll
            for (int j = 0; j < 16; ++j) {
                float h = fmaxf(fmaf(sW1[j], s, sb1[j]), 0.f);
                acc = fmaf(h, sW2[j * 16 + lane16], acc);
            }
            t[node * 16 + lane16] = acc * di;
        }
    }
}

// ---------------- layer 2: LDS 16-wide aggregate + relu + projection -> out ----------------
__global__ __launch_bounds__(BLK) void k_agg2(const unsigned int* __restrict__ binned2,
                                              const int* __restrict__ bucketBase,
                                              const float* __restrict__ t,
                                              const float* __restrict__ dinv,
                                              const float* __restrict__ b2,
                                              const float* __restrict__ Wl,
                                              const float* __restrict__ bl,
                                              float* __restrict__ out, int n) {
    __shared__ float sAcc[BW * 16];       // 32 KB
    __shared__ float sB2[16], sWl[16];
    int t0 = threadIdx.x;
    if (t0 < 16) { sB2[t0] = b2[t0]; sWl[t0] = Wl[t0]; }
    for (int k = t0; k < BW * 16; k += BLK) sAcc[k] = 0.f;
    __syncthreads();
    int b = blockIdx.x;
    int ebase = bucketBase[b];
    int ecnt = bucketBase[b + 1] - ebase;
    int lane16 = t0 & 15;
    int grp = t0 >> 4;                    // 32 groups, one edge each
    for (int i = grp; i < ecnt; i += 64) {
        unsigned int v0 = binned2[ebase + i];
        int i1 = i + 32;
        bool h1 = (i1 < ecnt);
        unsigned int v1 = h1 ? binned2[ebase + i1] : 0u;
        float f0 = t[(v0 >> BSHIFT) * 16 + lane16];
        float f1 = h1 ? t[(v1 >> BSHIFT) * 16 + lane16] : 0.f;
        atomicAdd(&sAcc[(v0 & (BW - 1)) * 16 + lane16], f0);
        if (h1) atomicAdd(&sAcc[(v1 & (BW - 1)) * 16 + lane16], f1);
    }
    __syncthreads();
    int nodeBase = b << BSHIFT;
    int nNodes = min(BW, n - nodeBase);
    for (int it = 0; it < BW / 32; ++it) {
        int ln = it * 32 + grp;
        if (ln < nNodes) {
            int node = nodeBase + ln;
            float di = dinv[node];
            float v = fmaf(di, sAcc[ln * 16 + lane16] + t[node * 16 + lane16], sB2[lane16]);
            v = fmaxf(v, 0.f);
            float p = v * sWl[lane16];
#pragma unroll
            for (int d = 1; d < 16; d <<= 1) p += __shfl_xor(p, d, 64);
            if (lane16 == 0) out[node] = p + bl[0];
        }
    }
}

extern "C" void kernel_launch(void* const* d_in, const int* in_sizes, int n_in,
                              void* d_out, int out_size, void* d_ws, size_t ws_size,
                              hipStream_t stream) {
    const float* x  = (const float*)d_in[0];
    const int*   ei = (const int*)d_in[1];
    const float* W1 = (const float*)d_in[2];
    const float* b1 = (const float*)d_in[3];
    const float* W2 = (const float*)d_in[4];
    const float* b2 = (const float*)d_in[5];
    const float* Wl = (const float*)d_in[6];
    const float* bl = (const float*)d_in[7];
    float* out = (float*)d_out;

    int n = in_sizes[0];
    int E = in_sizes[1] / 2;
    const int* srcA = ei;
    const int* dstA = ei + E;
    int NB = (n + BW - 1) >> BSHIFT;      // 391 for n=200000

    size_t o = 0;
    auto carve = [&](size_t bytes) {
        void* p = (char*)d_ws + o;
        o = (o + bytes + 255) & ~(size_t)255;
        return p;
    };
    int* bucketCount  = (int*)carve(NBMAX * 4);
    int* bucketBase   = (int*)carve((NBMAX + 1) * 4);
    int* bucketCursor = (int*)carve(NBMAX * 4);
    float* dinv       = (float*)carve((size_t)n * 4);
    float* xd         = (float*)carve((size_t)n * 4);
    unsigned int* binned  = (unsigned int*)carve((size_t)E * 4);
    unsigned int* binned2 = (unsigned int*)carve((size_t)E * 4);
    float* t = (float*)binned;            // alias: binned dead after k_sort
    (void)ws_size;

    hipMemsetAsync(bucketCount, 0, NBMAX * 4, stream);

    k_bhist<<<512, BLK, 0, stream>>>(dstA, bucketCount, E);
    k_bscan<<<1, BLK, 0, stream>>>(bucketCount, bucketBase, bucketCursor, NB, E);
    k_bin<<<(E + CHUNK - 1) / CHUNK, BLK, 0, stream>>>(srcA, dstA, bucketCursor, binned, E);
    k_sort<<<NB, BLK, 0, stream>>>(binned, bucketBase, x, binned2, dinv, xd, n);
    k_agg1<<<NB, BLK, 0, stream>>>(binned2, bucketBase, xd, dinv, W1, b1, W2, t, n);
    k_agg2<<<NB, BLK, 0, stream>>>(binned2, bucketBase, t, dinv, b2, Wl, bl, out, n);
}

// Round 4
// 236.611 us; speedup vs baseline: 3.6737x; 3.6737x over previous
//
#include <hip/hip_runtime.h>

#define BSHIFT 9
#define BW 512            // nodes per bucket == bins
#define BLK 512
#define CHUNK 4096

// ---- block-wide exclusive scan over BLK=512 ints (wave shfl + 8-entry LDS) ----
__device__ __forceinline__ int blockScanExcl512(int v, int tid, int* wsum) {
    int lane = tid & 63;
    int w = tid >> 6;                       // 8 waves
    int incl = v;
#pragma unroll
    for (int d = 1; d < 64; d <<= 1) {
        int u = __shfl_up(incl, d, 64);
        if (lane >= d) incl += u;
    }
    if (lane == 63) wsum[w] = incl;
    __syncthreads();
    if (tid < 64) {
        int x = (tid < 8) ? wsum[tid] : 0;
#pragma unroll
        for (int d = 1; d < 8; d <<= 1) {
            int u = __shfl_up(x, d, 64);
            if (lane >= d) x += u;
        }
        if (tid < 8) wsum[tid] = x;         // inclusive scan of wave totals
    }
    __syncthreads();
    int base = (w == 0) ? 0 : wsum[w - 1];
    return base + incl - v;
}

// ---------------- pass 1: bucket histogram (int4 loads, 4 LDS replicas) ----------------
__global__ __launch_bounds__(BLK) void k_bhist(const int* __restrict__ dst,
                                               int* __restrict__ bucketCount, int E) {
    __shared__ int h[4][BW];
    int t = threadIdx.x;
#pragma unroll
    for (int r = 0; r < 4; ++r) h[r][t] = 0;
    __syncthreads();
    int* hr = h[(t >> 6) & 3];
    int gtid = blockIdx.x * BLK + t;
    int stride = gridDim.x * BLK;
    const int4* dst4 = (const int4*)dst;
    int E4 = E >> 2;
    for (int i = gtid; i < E4; i += stride) {
        int4 d = dst4[i];
        atomicAdd(&hr[d.x >> BSHIFT], 1);
        atomicAdd(&hr[d.y >> BSHIFT], 1);
        atomicAdd(&hr[d.z >> BSHIFT], 1);
        atomicAdd(&hr[d.w >> BSHIFT], 1);
    }
    for (int i = (E4 << 2) + gtid; i < E; i += stride)
        atomicAdd(&hr[dst[i] >> BSHIFT], 1);
    __syncthreads();
    int s = h[0][t] + h[1][t] + h[2][t] + h[3][t];
    if (s) atomicAdd(&bucketCount[t], s);
}

// ---------------- pass 2: bucket scan (1 block) ----------------
__global__ __launch_bounds__(BLK) void k_bscan(const int* __restrict__ bucketCount,
                                               int* __restrict__ bucketBase,
                                               int* __restrict__ bucketCursor,
                                               int NB, int E) {
    __shared__ int wsum[8];
    int t = threadIdx.x;
    int v = (t < NB) ? bucketCount[t] : 0;
    int ex = blockScanExcl512(v, t, wsum);
    if (t < NB) { bucketBase[t] = ex; bucketCursor[t] = ex; }
    if (t == NB) bucketBase[t] = E;
}

// ---------------- pass 3: chunk counting-sort by dst-bucket, coalesced flush ----------------
__global__ __launch_bounds__(BLK) void k_bin(const int* __restrict__ src,
                                             const int* __restrict__ dst,
                                             int* __restrict__ bucketCursor,
                                             unsigned int* __restrict__ binned, int E) {
    __shared__ int h0[BW], h1[BW];
    __shared__ int excl[BW], cur[BW], gbase[BW];
    __shared__ unsigned int vals[CHUNK];
    __shared__ unsigned short bkt[CHUNK];
    __shared__ int wsum[8];
    int t = threadIdx.x;
    int base = blockIdx.x * CHUNK;
    int cnt = min(CHUNK, E - base);
    h0[t] = 0; h1[t] = 0;
    __syncthreads();
    int* hr = ((t >> 6) & 1) ? h1 : h0;

    int d8[8], s8[8];
    int myBase = base + t * 8;
    int nb = 0;
    if (myBase + 8 <= E) {
        const int4* dp = (const int4*)(dst + myBase);
        const int4* sp = (const int4*)(src + myBase);
        int4 a = dp[0], b = dp[1];
        d8[0]=a.x; d8[1]=a.y; d8[2]=a.z; d8[3]=a.w;
        d8[4]=b.x; d8[5]=b.y; d8[6]=b.z; d8[7]=b.w;
        int4 c = sp[0], e = sp[1];
        s8[0]=c.x; s8[1]=c.y; s8[2]=c.z; s8[3]=c.w;
        s8[4]=e.x; s8[5]=e.y; s8[6]=e.z; s8[7]=e.w;
        nb = 8;
    } else {
        for (int k = 0; k < 8; ++k) {
            int idx = myBase + k;
            if (idx < E) { d8[k] = dst[idx]; s8[k] = src[idx]; ++nb; }
        }
    }
    for (int k = 0; k < nb; ++k) atomicAdd(&hr[d8[k] >> BSHIFT], 1);
    __syncthreads();
    int hv = h0[t] + h1[t];
    int ex = blockScanExcl512(hv, t, wsum);
    excl[t] = ex;
    cur[t] = ex;
    if (hv) gbase[t] = atomicAdd(&bucketCursor[t], hv);
    __syncthreads();
    for (int k = 0; k < nb; ++k) {
        int b = d8[k] >> BSHIFT;
        int r = atomicAdd(&cur[b], 1);
        vals[r] = ((unsigned int)s8[k] << BSHIFT) | (unsigned int)(d8[k] & (BW - 1));
        bkt[r] = (unsigned short)b;
    }
    __syncthreads();
    for (int i = t; i < cnt; i += BLK) {
        int b = bkt[i];
        binned[gbase[b] + (i - excl[b])] = vals[i];
    }
}

// ---------------- pass 4: per-bucket per-node counting sort -> CSR (+deg/dinv/xd) ----------------
__global__ __launch_bounds__(BLK) void k_csr(const unsigned int* __restrict__ binned,
                                             const int* __restrict__ bucketBase,
                                             const float* __restrict__ x,
                                             int* __restrict__ csrOff,
                                             int* __restrict__ deg,
                                             float* __restrict__ dinv,
                                             float* __restrict__ xd,
                                             int* __restrict__ csrSrc, int n) {
    __shared__ int dh0[BW], dh1[BW];
    __shared__ int cursor[BW];
    __shared__ int wsum[8];
    int t = threadIdx.x;
    int b = blockIdx.x;
    int ebase = bucketBase[b];
    int ecnt = bucketBase[b + 1] - ebase;
    dh0[t] = 0; dh1[t] = 0;
    __syncthreads();
    int* dh = ((t >> 6) & 1) ? dh1 : dh0;
    for (int i = t; i < ecnt; i += BLK)
        atomicAdd(&dh[binned[ebase + i] & (BW - 1)], 1);
    __syncthreads();
    int c = dh0[t] + dh1[t];
    int ex = blockScanExcl512(c, t, wsum);
    cursor[t] = ex;
    int nodeBase = b << BSHIFT;
    if (t < min(BW, n - nodeBase)) {
        int node = nodeBase + t;
        csrOff[node] = ebase + ex;
        deg[node] = c;
        float r = rsqrtf((float)(c + 1));
        dinv[node] = r;
        xd[node] = x[node] * r;
    }
    __syncthreads();
    for (int i = t; i < ecnt; i += BLK) {
        unsigned int v = binned[ebase + i];
        int r = atomicAdd(&cursor[v & (BW - 1)], 1);
        csrSrc[ebase + r] = (int)(v >> BSHIFT);
    }
}

// ---------------- pass 5: layer-1 scalar aggregate -> sdi[n] = (s_i, dinv_i) ----------------
__global__ __launch_bounds__(BLK) void k_l1(const int* __restrict__ csrOff,
                                            const int* __restrict__ deg,
                                            const int* __restrict__ csrSrc,
                                            const float* __restrict__ xd,
                                            const float* __restrict__ dinv,
                                            float2* __restrict__ sdi, int n) {
    int tid = threadIdx.x;
    int lane16 = tid & 15;
    int node = blockIdx.x * (BLK / 16) + (tid >> 4);
    if (node >= n) return;
    int start = csrOff[node];
    int dc = deg[node];
    float u = 0.f;
    for (int e = lane16; e < dc; e += 16)
        u += xd[csrSrc[start + e]];
#pragma unroll
    for (int d = 1; d < 16; d <<= 1) u += __shfl_xor(u, d, 64);
    if (lane16 == 0) {
        float di = dinv[node];
        sdi[node] = make_float2(di * (u + xd[node]), di);
    }
}

// ---------------- pass 6: layer-2 via scalar gather + on-the-fly h recompute ----------------
// G_j = sum_src relu(W1[j]*s_src+b1[j])*dinv_src (+self);  A[k]=sum_j W2[j][k]*G_j
// out[i] = relu(dinv_i*A + b2) . Wl + bl
__global__ __launch_bounds__(BLK) void k_l2(const int* __restrict__ csrOff,
                                            const int* __restrict__ deg,
                                            const int* __restrict__ csrSrc,
                                            const float2* __restrict__ sdi,
                                            const float* __restrict__ W1,
                                            const float* __restrict__ b1,
                                            const float* __restrict__ W2,
                                            const float* __restrict__ b2,
                                            const float* __restrict__ Wl,
                                            const float* __restrict__ bl,
                                            float* __restrict__ out, int n) {
    __shared__ float sW2[256];
    int tid = threadIdx.x;
    int lane16 = tid & 15;
    if (tid < 256) sW2[tid] = W2[tid];
    __syncthreads();
    float w1 = W1[lane16], bb1 = b1[lane16], bb2 = b2[lane16], wl = Wl[lane16];
    int node = blockIdx.x * (BLK / 16) + (tid >> 4);
    if (node >= n) return;
    int start = csrOff[node];
    int dc = deg[node];
    float G = 0.f;
    int e = 0;
    for (; e + 4 <= dc; e += 4) {
        int s0 = csrSrc[start + e];
        int s1 = csrSrc[start + e + 1];
        int s2 = csrSrc[start + e + 2];
        int s3 = csrSrc[start + e + 3];
        float2 a0 = sdi[s0];
        float2 a1 = sdi[s1];
        float2 a2 = sdi[s2];
        float2 a3 = sdi[s3];
        G = fmaf(fmaxf(fmaf(w1, a0.x, bb1), 0.f), a0.y, G);
        G = fmaf(fmaxf(fmaf(w1, a1.x, bb1), 0.f), a1.y, G);
        G = fmaf(fmaxf(fmaf(w1, a2.x, bb1), 0.f), a2.y, G);
        G = fmaf(fmaxf(fmaf(w1, a3.x, bb1), 0.f), a3.y, G);
    }
    for (; e < dc; ++e) {
        float2 a = sdi[csrSrc[start + e]];
        G = fmaf(fmaxf(fmaf(w1, a.x, bb1), 0.f), a.y, G);
    }
    float2 aself = sdi[node];
    G = fmaf(fmaxf(fmaf(w1, aself.x, bb1), 0.f), aself.y, G);

    int gb = tid & 48;  // group base lane within wave
    float A = 0.f;
#pragma unroll
    for (int j = 0; j < 16; ++j) {
        float Gj = __shfl(G, gb + j, 64);
        A = fmaf(sW2[j * 16 + lane16], Gj, A);
    }
    float v = fmaxf(fmaf(aself.y, A, bb2), 0.f);
    float p = v * wl;
#pragma unroll
    for (int d = 1; d < 16; d <<= 1) p += __shfl_xor(p, d, 64);
    if (lane16 == 0) out[node] = p + bl[0];
}

extern "C" void kernel_launch(void* const* d_in, const int* in_sizes, int n_in,
                              void* d_out, int out_size, void* d_ws, size_t ws_size,
                              hipStream_t stream) {
    const float* x  = (const float*)d_in[0];
    const int*   ei = (const int*)d_in[1];
    const float* W1 = (const float*)d_in[2];
    const float* b1 = (const float*)d_in[3];
    const float* W2 = (const float*)d_in[4];
    const float* b2 = (const float*)d_in[5];
    const float* Wl = (const float*)d_in[6];
    const float* bl = (const float*)d_in[7];
    float* out = (float*)d_out;

    int n = in_sizes[0];
    int E = in_sizes[1] / 2;
    const int* srcA = ei;
    const int* dstA = ei + E;
    int NB = (n + BW - 1) >> BSHIFT;      // 391 for n=200000 (requires NB < 512)

    size_t o = 0;
    auto carve = [&](size_t bytes) {
        void* p = (char*)d_ws + o;
        o = (o + bytes + 255) & ~(size_t)255;
        return p;
    };
    int* bucketCount  = (int*)carve(BW * 4);
    int* bucketBase   = (int*)carve((BW + 1) * 4);
    int* bucketCursor = (int*)carve(BW * 4);
    int* csrOff       = (int*)carve((size_t)n * 4);
    int* deg          = (int*)carve((size_t)n * 4);
    float* dinv       = (float*)carve((size_t)n * 4);
    float* xd         = (float*)carve((size_t)n * 4);
    float2* sdi       = (float2*)carve((size_t)n * 8);
    unsigned int* binned = (unsigned int*)carve((size_t)E * 4);
    int* csrSrc       = (int*)carve((size_t)E * 4);
    (void)ws_size;

    hipMemsetAsync(bucketCount, 0, BW * 4, stream);

    k_bhist<<<512, BLK, 0, stream>>>(dstA, bucketCount, E);
    k_bscan<<<1, BLK, 0, stream>>>(bucketCount, bucketBase, bucketCursor, NB, E);
    k_bin<<<(E + CHUNK - 1) / CHUNK, BLK, 0, stream>>>(srcA, dstA, bucketCursor, binned, E);
    k_csr<<<NB, BLK, 0, stream>>>(binned, bucketBase, x, csrOff, deg, dinv, xd, csrSrc, n);

    int nodeBlocks = (n + (BLK / 16) - 1) / (BLK / 16);
    k_l1<<<nodeBlocks, BLK, 0, stream>>>(csrOff, deg, csrSrc, xd, dinv, sdi, n);
    k_l2<<<nodeBlocks, BLK, 0, stream>>>(csrOff, deg, csrSrc, sdi, W1, b1, W2, b2, Wl, bl, out, n);
}

// Round 5
// 198.773 us; speedup vs baseline: 4.3731x; 1.1904x over previous
//
#include <hip/hip_runtime.h>

#define BSHIFT 9
#define BW 512            // nodes per bucket == bins
#define BLK 512
#define CHUNK 4096

// ---- block-wide exclusive scan over BLK=512 ints (wave shfl + 8-entry LDS) ----
__device__ __forceinline__ int blockScanExcl512(int v, int tid, int* wsum) {
    int lane = tid & 63;
    int w = tid >> 6;                       // 8 waves
    int incl = v;
#pragma unroll
    for (int d = 1; d < 64; d <<= 1) {
        int u = __shfl_up(incl, d, 64);
        if (lane >= d) incl += u;
    }
    if (lane == 63) wsum[w] = incl;
    __syncthreads();
    if (tid < 64) {
        int x = (tid < 8) ? wsum[tid] : 0;
#pragma unroll
        for (int d = 1; d < 8; d <<= 1) {
            int u = __shfl_up(x, d, 64);
            if (lane >= d) x += u;
        }
        if (tid < 8) wsum[tid] = x;         // inclusive scan of wave totals
    }
    __syncthreads();
    int base = (w == 0) ? 0 : wsum[w - 1];
    return base + incl - v;
}

// ---------------- pass 1: bucket histogram (int4 loads, 4 LDS replicas) ----------------
__global__ __launch_bounds__(BLK) void k_bhist(const int* __restrict__ dst,
                                               int* __restrict__ bucketCount, int E) {
    __shared__ int h[4][BW];
    int t = threadIdx.x;
#pragma unroll
    for (int r = 0; r < 4; ++r) h[r][t] = 0;
    __syncthreads();
    int* hr = h[(t >> 6) & 3];
    int gtid = blockIdx.x * BLK + t;
    int stride = gridDim.x * BLK;
    const int4* dst4 = (const int4*)dst;
    int E4 = E >> 2;
    for (int i = gtid; i < E4; i += stride) {
        int4 d = dst4[i];
        atomicAdd(&hr[d.x >> BSHIFT], 1);
        atomicAdd(&hr[d.y >> BSHIFT], 1);
        atomicAdd(&hr[d.z >> BSHIFT], 1);
        atomicAdd(&hr[d.w >> BSHIFT], 1);
    }
    for (int i = (E4 << 2) + gtid; i < E; i += stride)
        atomicAdd(&hr[dst[i] >> BSHIFT], 1);
    __syncthreads();
    int s = h[0][t] + h[1][t] + h[2][t] + h[3][t];
    if (s) atomicAdd(&bucketCount[t], s);
}

// ---------------- pass 2: bucket scan (1 block) ----------------
__global__ __launch_bounds__(BLK) void k_bscan(const int* __restrict__ bucketCount,
                                               int* __restrict__ bucketBase,
                                               int* __restrict__ bucketCursor,
                                               int NB, int E) {
    __shared__ int wsum[8];
    int t = threadIdx.x;
    int v = (t < NB) ? bucketCount[t] : 0;
    int ex = blockScanExcl512(v, t, wsum);
    if (t < NB) { bucketBase[t] = ex; bucketCursor[t] = ex; }
    if (t == NB) bucketBase[t] = E;
}

// ---------------- pass 3: chunk counting-sort by dst-bucket, coalesced flush ----------------
__global__ __launch_bounds__(BLK) void k_bin(const int* __restrict__ src,
                                             const int* __restrict__ dst,
                                             int* __restrict__ bucketCursor,
                                             unsigned int* __restrict__ binned, int E) {
    __shared__ int h0[BW], h1[BW];
    __shared__ int excl[BW], cur[BW], gbase[BW];
    __shared__ unsigned int vals[CHUNK];
    __shared__ unsigned short bkt[CHUNK];
    __shared__ int wsum[8];
    int t = threadIdx.x;
    int base = blockIdx.x * CHUNK;
    int cnt = min(CHUNK, E - base);
    h0[t] = 0; h1[t] = 0;
    __syncthreads();
    int* hr = ((t >> 6) & 1) ? h1 : h0;

    int d8[8], s8[8];
    int myBase = base + t * 8;
    int nb = 0;
    if (myBase + 8 <= E) {
        const int4* dp = (const int4*)(dst + myBase);
        const int4* sp = (const int4*)(src + myBase);
        int4 a = dp[0], b = dp[1];
        d8[0]=a.x; d8[1]=a.y; d8[2]=a.z; d8[3]=a.w;
        d8[4]=b.x; d8[5]=b.y; d8[6]=b.z; d8[7]=b.w;
        int4 c = sp[0], e = sp[1];
        s8[0]=c.x; s8[1]=c.y; s8[2]=c.z; s8[3]=c.w;
        s8[4]=e.x; s8[5]=e.y; s8[6]=e.z; s8[7]=e.w;
        nb = 8;
    } else {
        for (int k = 0; k < 8; ++k) {
            int idx = myBase + k;
            if (idx < E) { d8[k] = dst[idx]; s8[k] = src[idx]; ++nb; }
        }
    }
    for (int k = 0; k < nb; ++k) atomicAdd(&hr[d8[k] >> BSHIFT], 1);
    __syncthreads();
    int hv = h0[t] + h1[t];
    int ex = blockScanExcl512(hv, t, wsum);
    excl[t] = ex;
    cur[t] = ex;
    if (hv) gbase[t] = atomicAdd(&bucketCursor[t], hv);
    __syncthreads();
    for (int k = 0; k < nb; ++k) {
        int b = d8[k] >> BSHIFT;
        int r = atomicAdd(&cur[b], 1);
        vals[r] = ((unsigned int)s8[k] << BSHIFT) | (unsigned int)(d8[k] & (BW - 1));
        bkt[r] = (unsigned short)b;
    }
    __syncthreads();
    for (int i = t; i < cnt; i += BLK) {
        int b = bkt[i];
        binned[gbase[b] + (i - excl[b])] = vals[i];
    }
}

// ---------------- pass 4: per-bucket per-node counting sort -> CSR (+deg/dinv/xd) ----------------
__global__ __launch_bounds__(BLK) void k_csr(const unsigned int* __restrict__ binned,
                                             const int* __restrict__ bucketBase,
                                             const float* __restrict__ x,
                                             int* __restrict__ csrOff,
                                             int* __restrict__ deg,
                                             float* __restrict__ dinv,
                                             float* __restrict__ xd,
                                             int* __restrict__ csrSrc, int n) {
    __shared__ int dh0[BW], dh1[BW];
    __shared__ int cursor[BW];
    __shared__ int wsum[8];
    int t = threadIdx.x;
    int b = blockIdx.x;
    int ebase = bucketBase[b];
    int ecnt = bucketBase[b + 1] - ebase;
    dh0[t] = 0; dh1[t] = 0;
    __syncthreads();
    int* dh = ((t >> 6) & 1) ? dh1 : dh0;
    for (int i = t; i < ecnt; i += BLK)
        atomicAdd(&dh[binned[ebase + i] & (BW - 1)], 1);
    __syncthreads();
    int c = dh0[t] + dh1[t];
    int ex = blockScanExcl512(c, t, wsum);
    cursor[t] = ex;
    int nodeBase = b << BSHIFT;
    if (t < min(BW, n - nodeBase)) {
        int node = nodeBase + t;
        csrOff[node] = ebase + ex;
        deg[node] = c;
        float r = rsqrtf((float)(c + 1));
        dinv[node] = r;
        xd[node] = x[node] * r;
    }
    __syncthreads();
    for (int i = t; i < ecnt; i += BLK) {
        unsigned int v = binned[ebase + i];
        int r = atomicAdd(&cursor[v & (BW - 1)], 1);
        csrSrc[ebase + r] = (int)(v >> BSHIFT);
    }
}

// ---------------- pass 5: layer-1 scalar aggregate -> sdi[n] = (s_i, dinv_i) ----------------
// 4 lanes per node: independent load streams, 2-step butterfly reduce.
__global__ __launch_bounds__(BLK) void k_l1(const int* __restrict__ csrOff,
                                            const int* __restrict__ deg,
                                            const int* __restrict__ csrSrc,
                                            const float* __restrict__ xd,
                                            const float* __restrict__ dinv,
                                            float2* __restrict__ sdi, int n) {
    int tid = threadIdx.x;
    int q = tid & 3;
    int node = blockIdx.x * (BLK / 4) + (tid >> 2);
    if (node >= n) return;
    int start = csrOff[node];
    int dc = deg[node];
    float u = 0.f;
    int e = q;
    for (; e + 4 < dc; e += 8) {
        int s0 = csrSrc[start + e];
        int s1 = csrSrc[start + e + 4];
        u += xd[s0] + xd[s1];
    }
    for (; e < dc; e += 4)
        u += xd[csrSrc[start + e]];
    u += __shfl_xor(u, 1, 64);
    u += __shfl_xor(u, 2, 64);
    if (q == 0) {
        float di = dinv[node];
        sdi[node] = make_float2(di * (u + xd[node]), di);
    }
}

// ---------------- pass 6: layer-2, 4 lanes per node, per-lane G[16] partials ----------------
// G_j = sum_src relu(W1[j]*s_src+b1[j])*dinv_src (+self);  A[k]=sum_j W2[j][k]*G_j
// out[i] = relu(dinv_i*A + b2) . Wl + bl
__global__ __launch_bounds__(BLK) void k_l2(const int* __restrict__ csrOff,
                                            const int* __restrict__ deg,
                                            const int* __restrict__ csrSrc,
                                            const float2* __restrict__ sdi,
                                            const float* __restrict__ W1,
                                            const float* __restrict__ b1,
                                            const float* __restrict__ W2,
                                            const float* __restrict__ b2,
                                            const float* __restrict__ Wl,
                                            const float* __restrict__ bl,
                                            float* __restrict__ out, int n) {
    __shared__ float sW2[256];
    int tid = threadIdx.x;
    if (tid < 256) sW2[tid] = W2[tid];
    int q = tid & 3;
    int node = blockIdx.x * (BLK / 4) + (tid >> 2);

    // per-lane W1 (SGPR ok: 1 sgpr operand allowed in v_fma) and b1 (pin to VGPR
    // so the unrolled fma doesn't need a per-use v_mov for a 2nd sgpr operand)
    float w1r[16], b1r[16];
#pragma unroll
    for (int j = 0; j < 16; ++j) {
        w1r[j] = W1[j];
        float bv = b1[j];
        asm volatile("" : "+v"(bv));
        b1r[j] = bv;
    }
    float4 b2q = *(const float4*)(b2 + 4 * q);
    float4 wlq = *(const float4*)(Wl + 4 * q);
    float blv = bl[0];
    __syncthreads();
    if (node >= n) return;

    int start = csrOff[node];
    int dc = deg[node];
    float G[16];
#pragma unroll
    for (int j = 0; j < 16; ++j) G[j] = 0.f;

    float2 aself = sdi[node];
    if (q == 0) {
#pragma unroll
        for (int j = 0; j < 16; ++j)
            G[j] = fmaf(fmaxf(fmaf(w1r[j], aself.x, b1r[j]), 0.f), aself.y, G[j]);
    }

    int e = q;
    for (; e + 4 < dc; e += 8) {
        int s0 = csrSrc[start + e];
        int s1 = csrSrc[start + e + 4];
        float2 a0 = sdi[s0];
        float2 a1 = sdi[s1];
#pragma unroll
        for (int j = 0; j < 16; ++j) {
            G[j] = fmaf(fmaxf(fmaf(w1r[j], a0.x, b1r[j]), 0.f), a0.y, G[j]);
            G[j] = fmaf(fmaxf(fmaf(w1r[j], a1.x, b1r[j]), 0.f), a1.y, G[j]);
        }
    }
    for (; e < dc; e += 4) {
        float2 a = sdi[csrSrc[start + e]];
#pragma unroll
        for (int j = 0; j < 16; ++j)
            G[j] = fmaf(fmaxf(fmaf(w1r[j], a.x, b1r[j]), 0.f), a.y, G[j]);
    }

    // 2-step butterfly: all 4 lanes of the quad end with the full G[16]
#pragma unroll
    for (int j = 0; j < 16; ++j) {
        G[j] += __shfl_xor(G[j], 1, 64);
        G[j] += __shfl_xor(G[j], 2, 64);
    }

    // W2 matvec: lane q owns output channels 4q..4q+3 (broadcast LDS reads)
    float4 A = make_float4(0.f, 0.f, 0.f, 0.f);
#pragma unroll
    for (int j = 0; j < 16; ++j) {
        float4 w = *(const float4*)(&sW2[j * 16 + 4 * q]);
        A.x = fmaf(w.x, G[j], A.x);
        A.y = fmaf(w.y, G[j], A.y);
        A.z = fmaf(w.z, G[j], A.z);
        A.w = fmaf(w.w, G[j], A.w);
    }

    float di = aself.y;
    float v0 = fmaxf(fmaf(di, A.x, b2q.x), 0.f);
    float v1 = fmaxf(fmaf(di, A.y, b2q.y), 0.f);
    float v2 = fmaxf(fmaf(di, A.z, b2q.z), 0.f);
    float v3 = fmaxf(fmaf(di, A.w, b2q.w), 0.f);
    float p = fmaf(v0, wlq.x, fmaf(v1, wlq.y, fmaf(v2, wlq.z, v3 * wlq.w)));
    p += __shfl_xor(p, 1, 64);
    p += __shfl_xor(p, 2, 64);
    if (q == 0) out[node] = p + blv;
}

extern "C" void kernel_launch(void* const* d_in, const int* in_sizes, int n_in,
                              void* d_out, int out_size, void* d_ws, size_t ws_size,
                              hipStream_t stream) {
    const float* x  = (const float*)d_in[0];
    const int*   ei = (const int*)d_in[1];
    const float* W1 = (const float*)d_in[2];
    const float* b1 = (const float*)d_in[3];
    const float* W2 = (const float*)d_in[4];
    const float* b2 = (const float*)d_in[5];
    const float* Wl = (const float*)d_in[6];
    const float* bl = (const float*)d_in[7];
    float* out = (float*)d_out;

    int n = in_sizes[0];
    int E = in_sizes[1] / 2;
    const int* srcA = ei;
    const int* dstA = ei + E;
    int NB = (n + BW - 1) >> BSHIFT;      // 391 for n=200000 (requires NB < 512)

    size_t o = 0;
    auto carve = [&](size_t bytes) {
        void* p = (char*)d_ws + o;
        o = (o + bytes + 255) & ~(size_t)255;
        return p;
    };
    int* bucketCount  = (int*)carve(BW * 4);
    int* bucketBase   = (int*)carve((BW + 1) * 4);
    int* bucketCursor = (int*)carve(BW * 4);
    int* csrOff       = (int*)carve((size_t)n * 4);
    int* deg          = (int*)carve((size_t)n * 4);
    float* dinv       = (float*)carve((size_t)n * 4);
    float* xd         = (float*)carve((size_t)n * 4);
    float2* sdi       = (float2*)carve((size_t)n * 8);
    unsigned int* binned = (unsigned int*)carve((size_t)E * 4);
    int* csrSrc       = (int*)carve((size_t)E * 4);
    (void)ws_size;

    hipMemsetAsync(bucketCount, 0, BW * 4, stream);

    k_bhist<<<512, BLK, 0, stream>>>(dstA, bucketCount, E);
    k_bscan<<<1, BLK, 0, stream>>>(bucketCount, bucketBase, bucketCursor, NB, E);
    k_bin<<<(E + CHUNK - 1) / CHUNK, BLK, 0, stream>>>(srcA, dstA, bucketCursor, binned, E);
    k_csr<<<NB, BLK, 0, stream>>>(binned, bucketBase, x, csrOff, deg, dinv, xd, csrSrc, n);

    int nodeBlocks = (n + (BLK / 4) - 1) / (BLK / 4);
    k_l1<<<nodeBlocks, BLK, 0, stream>>>(csrOff, deg, csrSrc, xd, dinv, sdi, n);
    k_l2<<<nodeBlocks, BLK, 0, stream>>>(csrOff, deg, csrSrc, sdi, W1, b1, W2, b2, Wl, bl, out, n);
}

// Round 6
// 166.530 us; speedup vs baseline: 5.2198x; 1.1936x over previous
//
#include <hip/hip_runtime.h>

#define BSHIFT 9
#define BW 512            // nodes per bucket == bins
#define BLK 512
#define CHUNK 4096
#define CSR_CAP 18432     // LDS staging capacity (expected bucket ~16.4K edges)

// ---- block-wide exclusive scan over BLK=512 ints (wave shfl + 8-entry LDS) ----
__device__ __forceinline__ int blockScanExcl512(int v, int tid, int* wsum) {
    int lane = tid & 63;
    int w = tid >> 6;                       // 8 waves
    int incl = v;
#pragma unroll
    for (int d = 1; d < 64; d <<= 1) {
        int u = __shfl_up(incl, d, 64);
        if (lane >= d) incl += u;
    }
    if (lane == 63) wsum[w] = incl;
    __syncthreads();
    if (tid < 64) {
        int x = (tid < 8) ? wsum[tid] : 0;
#pragma unroll
        for (int d = 1; d < 8; d <<= 1) {
            int u = __shfl_up(x, d, 64);
            if (lane >= d) x += u;
        }
        if (tid < 8) wsum[tid] = x;         // inclusive scan of wave totals
    }
    __syncthreads();
    int base = (w == 0) ? 0 : wsum[w - 1];
    return base + incl - v;
}

// ---------------- pass 1: bucket histogram (int4 loads, 4 LDS replicas) ----------------
__global__ __launch_bounds__(BLK) void k_bhist(const int* __restrict__ dst,
                                               int* __restrict__ bucketCount, int E) {
    __shared__ int h[4][BW];
    int t = threadIdx.x;
#pragma unroll
    for (int r = 0; r < 4; ++r) h[r][t] = 0;
    __syncthreads();
    int* hr = h[(t >> 6) & 3];
    int gtid = blockIdx.x * BLK + t;
    int stride = gridDim.x * BLK;
    const int4* dst4 = (const int4*)dst;
    int E4 = E >> 2;
    for (int i = gtid; i < E4; i += stride) {
        int4 d = dst4[i];
        atomicAdd(&hr[d.x >> BSHIFT], 1);
        atomicAdd(&hr[d.y >> BSHIFT], 1);
        atomicAdd(&hr[d.z >> BSHIFT], 1);
        atomicAdd(&hr[d.w >> BSHIFT], 1);
    }
    for (int i = (E4 << 2) + gtid; i < E; i += stride)
        atomicAdd(&hr[dst[i] >> BSHIFT], 1);
    __syncthreads();
    int s = h[0][t] + h[1][t] + h[2][t] + h[3][t];
    if (s) atomicAdd(&bucketCount[t], s);
}

// ---------------- pass 2: bucket scan (1 block) ----------------
__global__ __launch_bounds__(BLK) void k_bscan(const int* __restrict__ bucketCount,
                                               int* __restrict__ bucketBase,
                                               int* __restrict__ bucketCursor,
                                               int NB, int E) {
    __shared__ int wsum[8];
    int t = threadIdx.x;
    int v = (t < NB) ? bucketCount[t] : 0;
    int ex = blockScanExcl512(v, t, wsum);
    if (t < NB) { bucketBase[t] = ex; bucketCursor[t] = ex; }
    if (t == NB) bucketBase[t] = E;
}

// ---------------- pass 3: chunk counting-sort by dst-bucket, coalesced flush ----------------
__global__ __launch_bounds__(BLK) void k_bin(const int* __restrict__ src,
                                             const int* __restrict__ dst,
                                             int* __restrict__ bucketCursor,
                                             unsigned int* __restrict__ binned, int E) {
    __shared__ int h0[BW], h1[BW];
    __shared__ int excl[BW], cur[BW], gbase[BW];
    __shared__ unsigned int vals[CHUNK];
    __shared__ unsigned short bkt[CHUNK];
    __shared__ int wsum[8];
    int t = threadIdx.x;
    int base = blockIdx.x * CHUNK;
    int cnt = min(CHUNK, E - base);
    h0[t] = 0; h1[t] = 0;
    __syncthreads();
    int* hr = ((t >> 6) & 1) ? h1 : h0;

    int d8[8], s8[8];
    int myBase = base + t * 8;
    int nb = 0;
    if (myBase + 8 <= E) {
        const int4* dp = (const int4*)(dst + myBase);
        const int4* sp = (const int4*)(src + myBase);
        int4 a = dp[0], b = dp[1];
        d8[0]=a.x; d8[1]=a.y; d8[2]=a.z; d8[3]=a.w;
        d8[4]=b.x; d8[5]=b.y; d8[6]=b.z; d8[7]=b.w;
        int4 c = sp[0], e = sp[1];
        s8[0]=c.x; s8[1]=c.y; s8[2]=c.z; s8[3]=c.w;
        s8[4]=e.x; s8[5]=e.y; s8[6]=e.z; s8[7]=e.w;
        nb = 8;
    } else {
        for (int k = 0; k < 8; ++k) {
            int idx = myBase + k;
            if (idx < E) { d8[k] = dst[idx]; s8[k] = src[idx]; ++nb; }
        }
    }
    for (int k = 0; k < nb; ++k) atomicAdd(&hr[d8[k] >> BSHIFT], 1);
    __syncthreads();
    int hv = h0[t] + h1[t];
    int ex = blockScanExcl512(hv, t, wsum);
    excl[t] = ex;
    cur[t] = ex;
    if (hv) gbase[t] = atomicAdd(&bucketCursor[t], hv);
    __syncthreads();
    for (int k = 0; k < nb; ++k) {
        int b = d8[k] >> BSHIFT;
        int r = atomicAdd(&cur[b], 1);
        vals[r] = ((unsigned int)s8[k] << BSHIFT) | (unsigned int)(d8[k] & (BW - 1));
        bkt[r] = (unsigned short)b;
    }
    __syncthreads();
    for (int i = t; i < cnt; i += BLK) {
        int b = bkt[i];
        binned[gbase[b] + (i - excl[b])] = vals[i];
    }
}

// ---------------- pass 4: per-bucket per-node counting sort -> CSR (+deg/dinv/xd) ----------------
// LDS-staged output: scatter hits LDS, flush is a contiguous streaming write.
__global__ __launch_bounds__(BLK) void k_csr(const unsigned int* __restrict__ binned,
                                             const int* __restrict__ bucketBase,
                                             const float* __restrict__ x,
                                             int* __restrict__ csrOff,
                                             int* __restrict__ deg,
                                             float* __restrict__ dinv,
                                             float* __restrict__ xd,
                                             int* __restrict__ csrSrc, int n) {
    __shared__ int dh0[BW], dh1[BW];
    __shared__ int cursor[BW];
    __shared__ int wsum[8];
    __shared__ int stage[CSR_CAP];         // 72 KB
    int t = threadIdx.x;
    int b = blockIdx.x;
    int ebase = bucketBase[b];
    int ecnt = bucketBase[b + 1] - ebase;
    dh0[t] = 0; dh1[t] = 0;
    __syncthreads();
    int* dh = ((t >> 6) & 1) ? dh1 : dh0;
    for (int i = t; i < ecnt; i += BLK)
        atomicAdd(&dh[binned[ebase + i] & (BW - 1)], 1);
    __syncthreads();
    int c = dh0[t] + dh1[t];
    int ex = blockScanExcl512(c, t, wsum);
    cursor[t] = ex;
    int nodeBase = b << BSHIFT;
    if (t < min(BW, n - nodeBase)) {
        int node = nodeBase + t;
        csrOff[node] = ebase + ex;
        deg[node] = c;
        float r = rsqrtf((float)(c + 1));
        dinv[node] = r;
        xd[node] = x[node] * r;
    }
    __syncthreads();
    for (int i = t; i < ecnt; i += BLK) {
        unsigned int v = binned[ebase + i];
        int r = atomicAdd(&cursor[v & (BW - 1)], 1);
        int sv = (int)(v >> BSHIFT);
        if (r < CSR_CAP) stage[r] = sv;    // normal path
        else csrSrc[ebase + r] = sv;       // overflow fallback (correctness)
    }
    __syncthreads();
    int m = min(ecnt, CSR_CAP);
    for (int i = t; i < m; i += BLK)
        csrSrc[ebase + i] = stage[i];
}

// ---------------- pass 5: layer-1 scalar aggregate -> sdi[n] = (s_i, dinv_i) ----------------
__global__ __launch_bounds__(BLK) void k_l1(const int* __restrict__ csrOff,
                                            const int* __restrict__ deg,
                                            const int* __restrict__ csrSrc,
                                            const float* __restrict__ xd,
                                            const float* __restrict__ dinv,
                                            float2* __restrict__ sdi, int n) {
    int tid = threadIdx.x;
    int q = tid & 3;
    int node = blockIdx.x * (BLK / 4) + (tid >> 2);
    if (node >= n) return;
    int start = csrOff[node];
    int dc = deg[node];
    float u = 0.f;
    int e = q;
    for (; e + 4 < dc; e += 8) {
        int s0 = csrSrc[start + e];
        int s1 = csrSrc[start + e + 4];
        u += xd[s0] + xd[s1];
    }
    for (; e < dc; e += 4)
        u += xd[csrSrc[start + e]];
    u += __shfl_xor(u, 1, 64);
    u += __shfl_xor(u, 2, 64);
    if (q == 0) {
        float di = dinv[node];
        sdi[node] = make_float2(di * (u + xd[node]), di);
    }
}

// ---------------- pass 6: layer-2, 4 lanes per node, per-lane G[16] partials ----------------
__global__ __launch_bounds__(BLK) void k_l2(const int* __restrict__ csrOff,
                                            const int* __restrict__ deg,
                                            const int* __restrict__ csrSrc,
                                            const float2* __restrict__ sdi,
                                            const float* __restrict__ W1,
                                            const float* __restrict__ b1,
                                            const float* __restrict__ W2,
                                            const float* __restrict__ b2,
                                            const float* __restrict__ Wl,
                                            const float* __restrict__ bl,
                                            float* __restrict__ out, int n) {
    __shared__ float sW2[256];
    int tid = threadIdx.x;
    if (tid < 256) sW2[tid] = W2[tid];
    int q = tid & 3;
    int node = blockIdx.x * (BLK / 4) + (tid >> 2);

    float w1r[16], b1r[16];
#pragma unroll
    for (int j = 0; j < 16; ++j) {
        w1r[j] = W1[j];
        float bv = b1[j];
        asm volatile("" : "+v"(bv));
        b1r[j] = bv;
    }
    float4 b2q = *(const float4*)(b2 + 4 * q);
    float4 wlq = *(const float4*)(Wl + 4 * q);
    float blv = bl[0];
    __syncthreads();
    if (node >= n) return;

    int start = csrOff[node];
    int dc = deg[node];
    float G[16];
#pragma unroll
    for (int j = 0; j < 16; ++j) G[j] = 0.f;

    float2 aself = sdi[node];
    if (q == 0) {
#pragma unroll
        for (int j = 0; j < 16; ++j)
            G[j] = fmaf(fmaxf(fmaf(w1r[j], aself.x, b1r[j]), 0.f), aself.y, G[j]);
    }

    int e = q;
    for (; e + 4 < dc; e += 8) {
        int s0 = csrSrc[start + e];
        int s1 = csrSrc[start + e + 4];
        float2 a0 = sdi[s0];
        float2 a1 = sdi[s1];
#pragma unroll
        for (int j = 0; j < 16; ++j) {
            G[j] = fmaf(fmaxf(fmaf(w1r[j], a0.x, b1r[j]), 0.f), a0.y, G[j]);
            G[j] = fmaf(fmaxf(fmaf(w1r[j], a1.x, b1r[j]), 0.f), a1.y, G[j]);
        }
    }
    for (; e < dc; e += 4) {
        float2 a = sdi[csrSrc[start + e]];
#pragma unroll
        for (int j = 0; j < 16; ++j)
            G[j] = fmaf(fmaxf(fmaf(w1r[j], a.x, b1r[j]), 0.f), a.y, G[j]);
    }

#pragma unroll
    for (int j = 0; j < 16; ++j) {
        G[j] += __shfl_xor(G[j], 1, 64);
        G[j] += __shfl_xor(G[j], 2, 64);
    }

    float4 A = make_float4(0.f, 0.f, 0.f, 0.f);
#pragma unroll
    for (int j = 0; j < 16; ++j) {
        float4 w = *(const float4*)(&sW2[j * 16 + 4 * q]);
        A.x = fmaf(w.x, G[j], A.x);
        A.y = fmaf(w.y, G[j], A.y);
        A.z = fmaf(w.z, G[j], A.z);
        A.w = fmaf(w.w, G[j], A.w);
    }

    float di = aself.y;
    float v0 = fmaxf(fmaf(di, A.x, b2q.x), 0.f);
    float v1 = fmaxf(fmaf(di, A.y, b2q.y), 0.f);
    float v2 = fmaxf(fmaf(di, A.z, b2q.z), 0.f);
    float v3 = fmaxf(fmaf(di, A.w, b2q.w), 0.f);
    float p = fmaf(v0, wlq.x, fmaf(v1, wlq.y, fmaf(v2, wlq.z, v3 * wlq.w)));
    p += __shfl_xor(p, 1, 64);
    p += __shfl_xor(p, 2, 64);
    if (q == 0) out[node] = p + blv;
}

extern "C" void kernel_launch(void* const* d_in, const int* in_sizes, int n_in,
                              void* d_out, int out_size, void* d_ws, size_t ws_size,
                              hipStream_t stream) {
    const float* x  = (const float*)d_in[0];
    const int*   ei = (const int*)d_in[1];
    const float* W1 = (const float*)d_in[2];
    const float* b1 = (const float*)d_in[3];
    const float* W2 = (const float*)d_in[4];
    const float* b2 = (const float*)d_in[5];
    const float* Wl = (const float*)d_in[6];
    const float* bl = (const float*)d_in[7];
    float* out = (float*)d_out;

    int n = in_sizes[0];
    int E = in_sizes[1] / 2;
    const int* srcA = ei;
    const int* dstA = ei + E;
    int NB = (n + BW - 1) >> BSHIFT;      // 391 for n=200000 (requires NB < 512)

    size_t o = 0;
    auto carve = [&](size_t bytes) {
        void* p = (char*)d_ws + o;
        o = (o + bytes + 255) & ~(size_t)255;
        return p;
    };
    int* bucketCount  = (int*)carve(BW * 4);
    int* bucketBase   = (int*)carve((BW + 1) * 4);
    int* bucketCursor = (int*)carve(BW * 4);
    int* csrOff       = (int*)carve((size_t)n * 4);
    int* deg          = (int*)carve((size_t)n * 4);
    float* dinv       = (float*)carve((size_t)n * 4);
    float* xd         = (float*)carve((size_t)n * 4);
    float2* sdi       = (float2*)carve((size_t)n * 8);
    unsigned int* binned = (unsigned int*)carve((size_t)E * 4);
    int* csrSrc       = (int*)carve((size_t)E * 4);
    (void)ws_size;

    hipMemsetAsync(bucketCount, 0, BW * 4, stream);

    k_bhist<<<512, BLK, 0, stream>>>(dstA, bucketCount, E);
    k_bscan<<<1, BLK, 0, stream>>>(bucketCount, bucketBase, bucketCursor, NB, E);
    k_bin<<<(E + CHUNK - 1) / CHUNK, BLK, 0, stream>>>(srcA, dstA, bucketCursor, binned, E);
    k_csr<<<NB, BLK, 0, stream>>>(binned, bucketBase, x, csrOff, deg, dinv, xd, csrSrc, n);

    int nodeBlocks = (n + (BLK / 4) - 1) / (BLK / 4);
    k_l1<<<nodeBlocks, BLK, 0, stream>>>(csrOff, deg, csrSrc, xd, dinv, sdi, n);
    k_l2<<<nodeBlocks, BLK, 0, stream>>>(csrOff, deg, csrSrc, sdi, W1, b1, W2, b2, Wl, bl, out, n);
}